// Round 3
// baseline (49.562 us; speedup 1.0000x reference)
//
#include <hip/hip_runtime.h>
#include <stdint.h>

#define N_PROP    262144
#define N_GT      128
#define N_ALL     (N_PROP + N_GT)      // 262272 (even)
#define NFG_MAX   128
#define NROIS_OUT 512
#define BLK       256
#define R         2
#define ITEMS     (BLK * R)            // 512 items per K1 block
#define NB1       ((N_ALL + ITEMS - 1) / ITEMS)   // 513 K1 blocks
#define NCNT      1025                 // count entries, 256 items each
#define NBLOCKS2  1025                 // K2 blocks (256 items each)

// ---------------- workspace layout (bytes) ----------------
// packed : uint16 [N_ALL]  @ 0        ((flag<<8)|argmax), written as u32 pairs
// cnt    : uint32 [NCNT]   @ 524544   ((bg<<16)|fg per 256-item chunk)
#define OFF_PACKED 0
#define OFF_CNT    524544

// K1: 2 rois/thread; GT staged as float4+area in LDS (2 ds_reads per GT).
__global__ __launch_bounds__(BLK) void k_iou(
    const float* __restrict__ rois, const float* __restrict__ gt,
    uint32_t* __restrict__ packed2, uint32_t* __restrict__ cnt)
{
    __shared__ float4 sg[N_GT];
    __shared__ float  sga[N_GT];
    int tid = threadIdx.x;
    if (tid < N_GT) {
        float4 g = *reinterpret_cast<const float4*>(gt + 4 * tid);
        sg[tid] = g;
        sga[tid] = __fmul_rn(__fadd_rn(__fsub_rn(g.z, g.x), 1.0f),
                             __fadd_rn(__fsub_rn(g.w, g.y), 1.0f));
    }
    __syncthreads();

    int i0 = blockIdx.x * ITEMS + tid * 2;     // even; pair never straddles rois/gt
    bool v = (i0 < N_ALL);
    float4 b0 = {0,0,0,0}, b1 = {0,0,0,0};
    if (v) {
        const float* p = (i0 < N_PROP) ? (rois + 4 * (size_t)i0)
                                       : (gt + 4 * (size_t)(i0 - N_PROP));
        b0 = *reinterpret_cast<const float4*>(p);
        b1 = *reinterpret_cast<const float4*>(p + 4);
    }
    float a0 = __fmul_rn(__fadd_rn(__fsub_rn(b0.z, b0.x), 1.0f),
                         __fadd_rn(__fsub_rn(b0.w, b0.y), 1.0f));
    float a1 = __fmul_rn(__fadd_rn(__fsub_rn(b1.z, b1.x), 1.0f),
                         __fadd_rn(__fsub_rn(b1.w, b1.y), 1.0f));

    float best0 = -1.0f, best1 = -1.0f;
    int bj0 = 0, bj1 = 0;
    if (v) {
        #pragma unroll 2
        for (int j = 0; j < N_GT; ++j) {
            float4 g = sg[j];
            float ga = sga[j];
            // roi 0
            {
                float iw = fmaxf(__fadd_rn(__fsub_rn(fminf(b0.z, g.z), fmaxf(b0.x, g.x)), 1.0f), 0.0f);
                float ih = fmaxf(__fadd_rn(__fsub_rn(fminf(b0.w, g.w), fmaxf(b0.y, g.y)), 1.0f), 0.0f);
                float inter = __fmul_rn(iw, ih);
                float denom = __fsub_rn(__fadd_rn(a0, ga), inter);
                float iou = __fdiv_rn(inter, denom);
                if (iou > best0) { best0 = iou; bj0 = j; }   // strict > == first-max
            }
            // roi 1
            {
                float iw = fmaxf(__fadd_rn(__fsub_rn(fminf(b1.z, g.z), fmaxf(b1.x, g.x)), 1.0f), 0.0f);
                float ih = fmaxf(__fadd_rn(__fsub_rn(fminf(b1.w, g.w), fmaxf(b1.y, g.y)), 1.0f), 0.0f);
                float inter = __fmul_rn(iw, ih);
                float denom = __fsub_rn(__fadd_rn(a1, ga), inter);
                float iou = __fdiv_rn(inter, denom);
                if (iou > best1) { best1 = iou; bj1 = j; }
            }
        }
    }
    bool fg0 = v && (best0 > 0.5f);
    bool bg0 = v && (best0 > 0.1f) && (best0 < 0.5f);
    bool fg1 = v && (best1 > 0.5f);
    bool bg1 = v && (best1 > 0.1f) && (best1 < 0.5f);
    if (v) {
        uint32_t p0 = (uint32_t)((fg0 ? 0 : (bg0 ? 1 : 2)) << 8) | (uint32_t)bj0;
        uint32_t p1 = (uint32_t)((fg1 ? 0 : (bg1 ? 1 : 2)) << 8) | (uint32_t)bj1;
        packed2[i0 >> 1] = (p1 << 16) | p0;
    }

    unsigned long long mf0 = __ballot(fg0 ? 1 : 0), mf1 = __ballot(fg1 ? 1 : 0);
    unsigned long long mb0 = __ballot(bg0 ? 1 : 0), mb1 = __ballot(bg1 ? 1 : 0);
    __shared__ int sF[4], sB[4];
    int lane = tid & 63, w = tid >> 6;
    if (lane == 0) {
        sF[w] = __popcll(mf0) + __popcll(mf1);
        sB[w] = __popcll(mb0) + __popcll(mb1);
    }
    __syncthreads();
    // wave w covers items [base+128w, base+128w+128): waves {0,1} -> cnt[2b], {2,3} -> cnt[2b+1]
    if (tid == 0)
        cnt[2 * blockIdx.x] = ((uint32_t)(sB[0] + sB[1]) << 16) | (uint32_t)(sF[0] + sF[1]);
    if (tid == 128 && 2 * blockIdx.x + 1 < NCNT)
        cnt[2 * blockIdx.x + 1] = ((uint32_t)(sB[2] + sB[3]) << 16) | (uint32_t)(sF[2] + sF[3]);
}

// K2: per-block redundant global prefix over cnt[] + in-block ballot scan,
// stable-argsort position reconstruction + gather + bbox_transform. (Unchanged logic.)
__global__ __launch_bounds__(BLK) void k_select(
    const float* __restrict__ rois, const float* __restrict__ gt,
    const int* __restrict__ labels,
    const uint16_t* __restrict__ packed, const uint32_t* __restrict__ cnt,
    float* __restrict__ out)
{
    int tid = threadIdx.x, bid = blockIdx.x;
    int i = bid * BLK + tid;
    bool valid = (i < N_ALL);
    uint16_t p = valid ? packed[i] : (uint16_t)(2 << 8);
    int flagv = p >> 8;
    int g = p & 0xFF;
    bool isfg = valid && (flagv == 0);
    bool isbg = valid && (flagv == 1);

    // global totals + prefix(< bid) over 256-item chunk counts (L2-hot)
    int totF = 0, totB = 0, preF = 0, preB = 0;
    for (int j = tid; j < NCNT; j += BLK) {
        uint32_t c = cnt[j];
        int f = (int)(c & 0xFFFFu), b = (int)(c >> 16);
        totF += f; totB += b;
        if (j < bid) { preF += f; preB += b; }
    }
    #pragma unroll
    for (int off = 32; off > 0; off >>= 1) {
        totF += __shfl_down(totF, off, 64);
        totB += __shfl_down(totB, off, 64);
        preF += __shfl_down(preF, off, 64);
        preB += __shfl_down(preB, off, 64);
    }
    __shared__ int sTF[4], sTB[4], sPF[4], sPB[4];
    __shared__ int sWF[4], sWB[4];
    int lane = tid & 63, w = tid >> 6;
    if (lane == 0) { sTF[w] = totF; sTB[w] = totB; sPF[w] = preF; sPB[w] = preB; }

    unsigned long long mf = __ballot(isfg ? 1 : 0);
    unsigned long long mb = __ballot(isbg ? 1 : 0);
    unsigned long long lemask = (lane == 63) ? ~0ull : ((1ull << (lane + 1)) - 1ull);
    int inclF = __popcll(mf & lemask);
    int inclB = __popcll(mb & lemask);
    if (lane == 0) { sWF[w] = __popcll(mf); sWB[w] = __popcll(mb); }
    __syncthreads();

    totF = sTF[0] + sTF[1] + sTF[2] + sTF[3];
    totB = sTB[0] + sTB[1] + sTB[2] + sTB[3];
    preF = sPF[0] + sPF[1] + sPF[2] + sPF[3];
    preB = sPB[0] + sPB[1] + sPB[2] + sPB[3];
    int wPreF = 0, wPreB = 0;
    for (int k = 0; k < 4; ++k) {
        if (k < w) { wPreF += sWF[k]; wPreB += sWB[k]; }
    }
    if (!valid) return;

    int NF  = totF < NFG_MAX ? totF : NFG_MAX;
    int LIM = NROIS_OUT - NF;
    int NB  = totB < LIM ? totB : LIM;

    int fgCum = preF + wPreF + inclF;
    int bgCum = preB + wPreB + inclB;

    int pos;
    if (isfg && fgCum <= NFG_MAX) {
        pos = fgCum - 1;
    } else if (isbg && bgCum <= LIM) {
        pos = NF + bgCum - 1;
    } else {
        int selF = fgCum < NFG_MAX ? fgCum : NFG_MAX;
        int selB = bgCum < LIM ? bgCum : LIM;
        int restCum = (i + 1) - selF - selB;
        pos = NF + NB + restCum - 1;
    }
    if (pos >= NROIS_OUT) return;

    const float* rp = (i < N_PROP) ? (rois + 4 * (size_t)i)
                                   : (gt + 4 * (size_t)(i - N_PROP));
    float4 r = *reinterpret_cast<const float4*>(rp);
    float4 gb = *reinterpret_cast<const float4*>(gt + 4 * (size_t)g);

    float wdt = __fadd_rn(__fsub_rn(r.z, r.x), 1.0f);
    float hgt = __fadd_rn(__fsub_rn(r.w, r.y), 1.0f);
    float cx  = __fadd_rn(r.x, __fmul_rn(0.5f, wdt));
    float cy  = __fadd_rn(r.y, __fmul_rn(0.5f, hgt));
    float gw  = __fadd_rn(__fsub_rn(gb.z, gb.x), 1.0f);
    float gh  = __fadd_rn(__fsub_rn(gb.w, gb.y), 1.0f);
    float gcx = __fadd_rn(gb.x, __fmul_rn(0.5f, gw));
    float gcy = __fadd_rn(gb.y, __fmul_rn(0.5f, gh));

    float d0 = __fdiv_rn(__fdiv_rn(__fsub_rn(gcx, cx), wdt), 0.2f);
    float d1 = __fdiv_rn(__fdiv_rn(__fsub_rn(gcy, cy), hgt), 0.2f);
    float d2 = __fdiv_rn(logf(__fdiv_rn(gw, wdt)), 0.2f);
    float d3 = __fdiv_rn(logf(__fdiv_rn(gh, hgt)), 0.2f);

    out[4 * pos + 0] = r.x;
    out[4 * pos + 1] = r.y;
    out[4 * pos + 2] = r.z;
    out[4 * pos + 3] = r.w;
    out[2048 + 4 * pos + 0] = d0;
    out[2048 + 4 * pos + 1] = d1;
    out[2048 + 4 * pos + 2] = d2;
    out[2048 + 4 * pos + 3] = d3;
    out[4096 + pos] = (float)labels[g];
}

extern "C" void kernel_launch(void* const* d_in, const int* in_sizes, int n_in,
                              void* d_out, int out_size, void* d_ws, size_t ws_size,
                              hipStream_t stream)
{
    const float* rois   = (const float*)d_in[0];
    const float* gt     = (const float*)d_in[1];
    const int*   labels = (const int*)d_in[2];
    float* out = (float*)d_out;

    char* ws = (char*)d_ws;
    uint32_t* packed2 = (uint32_t*)(ws + OFF_PACKED);
    uint16_t* packed  = (uint16_t*)(ws + OFF_PACKED);
    uint32_t* cnt     = (uint32_t*)(ws + OFF_CNT);

    k_iou<<<NB1, BLK, 0, stream>>>(rois, gt, packed2, cnt);
    k_select<<<NBLOCKS2, BLK, 0, stream>>>(rois, gt, labels, packed, cnt, out);
}

// Round 4
// 40.187 us; speedup vs baseline: 1.2333x; 1.2333x over previous
//
#include <hip/hip_runtime.h>
#include <stdint.h>

#define N_PROP    262144
#define N_GT      128
#define N_ALL     (N_PROP + N_GT)      // 262272
#define NFG_MAX   128
#define NROIS_OUT 512
#define BLK       256
#define NBLOCKS   ((N_ALL + BLK - 1) / BLK)   // 1025

// ---------------- workspace layout (bytes) ----------------
// packed : uint16 [N_ALL]   @ 0        ((flag<<8)|argmax)
// cnt    : uint32 [NBLOCKS] @ 524544   ((bg<<16)|fg per 256-item chunk)
#define OFF_PACKED 0
#define OFF_CNT    524544

// K1: 1 roi/thread, 16 waves/CU. GT coords read via wave-uniform global loads
// (-> s_load_dwordx4 on the scalar pipe / constant cache); only the
// precomputed GT area lives in LDS (1x ds_read_b32 per iter).
__global__ __launch_bounds__(BLK) void k_iou(
    const float* __restrict__ rois, const float* __restrict__ gt,
    uint16_t* __restrict__ packed, uint32_t* __restrict__ cnt)
{
    __shared__ float sga[N_GT];
    int tid = threadIdx.x;
    if (tid < N_GT) {
        float4 g = *reinterpret_cast<const float4*>(gt + 4 * tid);
        sga[tid] = __fmul_rn(__fadd_rn(__fsub_rn(g.z, g.x), 1.0f),
                             __fadd_rn(__fsub_rn(g.w, g.y), 1.0f));
    }
    __syncthreads();

    int i = blockIdx.x * BLK + tid;
    bool v = (i < N_ALL);
    float4 b = {0, 0, 0, 0};
    if (v) {
        const float* p = (i < N_PROP) ? (rois + 4 * (size_t)i)
                                      : (gt + 4 * (size_t)(i - N_PROP));
        b = *reinterpret_cast<const float4*>(p);
    }
    float a = __fmul_rn(__fadd_rn(__fsub_rn(b.z, b.x), 1.0f),
                        __fadd_rn(__fsub_rn(b.w, b.y), 1.0f));

    float best = -1.0f; int bestj = 0;
    if (v) {
        #pragma unroll 4
        for (int j = 0; j < N_GT; ++j) {
            // wave-uniform -> scalar loads (constant cache), no LDS/VMEM pressure
            float gx = gt[4 * j + 0];
            float gy = gt[4 * j + 1];
            float gz = gt[4 * j + 2];
            float gw = gt[4 * j + 3];
            float ga = sga[j];
            float iw = fmaxf(__fadd_rn(__fsub_rn(fminf(b.z, gz), fmaxf(b.x, gx)), 1.0f), 0.0f);
            float ih = fmaxf(__fadd_rn(__fsub_rn(fminf(b.w, gw), fmaxf(b.y, gy)), 1.0f), 0.0f);
            float inter = __fmul_rn(iw, ih);
            float denom = __fsub_rn(__fadd_rn(a, ga), inter);
            float iou = __fdiv_rn(inter, denom);
            if (iou > best) { best = iou; bestj = j; }   // strict > == first-max (jnp.argmax)
        }
    }
    bool fg = v && (best > 0.5f);
    bool bg = v && (best > 0.1f) && (best < 0.5f);
    if (v) {
        int flagv = fg ? 0 : (bg ? 1 : 2);
        packed[i] = (uint16_t)((flagv << 8) | bestj);
    }
    unsigned long long mf = __ballot(fg ? 1 : 0);
    unsigned long long mb = __ballot(bg ? 1 : 0);
    __shared__ int sF[BLK / 64], sB[BLK / 64];
    int lane = tid & 63, w = tid >> 6;
    if (lane == 0) { sF[w] = __popcll(mf); sB[w] = __popcll(mb); }
    __syncthreads();
    if (tid == 0) {
        int tf = 0, tb = 0;
        for (int k = 0; k < BLK / 64; ++k) { tf += sF[k]; tb += sB[k]; }
        cnt[blockIdx.x] = ((uint32_t)tb << 16) | (uint32_t)tf;
    }
}

// K2: per-block redundant global prefix over cnt[] + in-block ballot scan,
// stable-argsort position reconstruction + gather + bbox_transform. (Unchanged.)
__global__ __launch_bounds__(BLK) void k_select(
    const float* __restrict__ rois, const float* __restrict__ gt,
    const int* __restrict__ labels,
    const uint16_t* __restrict__ packed, const uint32_t* __restrict__ cnt,
    float* __restrict__ out)
{
    int tid = threadIdx.x, bid = blockIdx.x;
    int i = bid * BLK + tid;
    bool valid = (i < N_ALL);
    uint16_t p = valid ? packed[i] : (uint16_t)(2 << 8);
    int flagv = p >> 8;
    int g = p & 0xFF;
    bool isfg = valid && (flagv == 0);
    bool isbg = valid && (flagv == 1);

    int totF = 0, totB = 0, preF = 0, preB = 0;
    for (int j = tid; j < NBLOCKS; j += BLK) {
        uint32_t c = cnt[j];
        int f = (int)(c & 0xFFFFu), bb = (int)(c >> 16);
        totF += f; totB += bb;
        if (j < bid) { preF += f; preB += bb; }
    }
    #pragma unroll
    for (int off = 32; off > 0; off >>= 1) {
        totF += __shfl_down(totF, off, 64);
        totB += __shfl_down(totB, off, 64);
        preF += __shfl_down(preF, off, 64);
        preB += __shfl_down(preB, off, 64);
    }
    __shared__ int sTF[4], sTB[4], sPF[4], sPB[4];
    __shared__ int sWF[4], sWB[4];
    int lane = tid & 63, w = tid >> 6;
    if (lane == 0) { sTF[w] = totF; sTB[w] = totB; sPF[w] = preF; sPB[w] = preB; }

    unsigned long long mf = __ballot(isfg ? 1 : 0);
    unsigned long long mb = __ballot(isbg ? 1 : 0);
    unsigned long long lemask = (lane == 63) ? ~0ull : ((1ull << (lane + 1)) - 1ull);
    int inclF = __popcll(mf & lemask);
    int inclB = __popcll(mb & lemask);
    if (lane == 0) { sWF[w] = __popcll(mf); sWB[w] = __popcll(mb); }
    __syncthreads();

    totF = sTF[0] + sTF[1] + sTF[2] + sTF[3];
    totB = sTB[0] + sTB[1] + sTB[2] + sTB[3];
    preF = sPF[0] + sPF[1] + sPF[2] + sPF[3];
    preB = sPB[0] + sPB[1] + sPB[2] + sPB[3];
    int wPreF = 0, wPreB = 0;
    for (int k = 0; k < 4; ++k) {
        if (k < w) { wPreF += sWF[k]; wPreB += sWB[k]; }
    }
    if (!valid) return;

    int NF  = totF < NFG_MAX ? totF : NFG_MAX;
    int LIM = NROIS_OUT - NF;
    int NB  = totB < LIM ? totB : LIM;

    int fgCum = preF + wPreF + inclF;
    int bgCum = preB + wPreB + inclB;

    int pos;
    if (isfg && fgCum <= NFG_MAX) {
        pos = fgCum - 1;
    } else if (isbg && bgCum <= LIM) {
        pos = NF + bgCum - 1;
    } else {
        int selF = fgCum < NFG_MAX ? fgCum : NFG_MAX;
        int selB = bgCum < LIM ? bgCum : LIM;
        int restCum = (i + 1) - selF - selB;
        pos = NF + NB + restCum - 1;
    }
    if (pos >= NROIS_OUT) return;

    const float* rp = (i < N_PROP) ? (rois + 4 * (size_t)i)
                                   : (gt + 4 * (size_t)(i - N_PROP));
    float4 r = *reinterpret_cast<const float4*>(rp);
    float4 gb = *reinterpret_cast<const float4*>(gt + 4 * (size_t)g);

    float wdt = __fadd_rn(__fsub_rn(r.z, r.x), 1.0f);
    float hgt = __fadd_rn(__fsub_rn(r.w, r.y), 1.0f);
    float cx  = __fadd_rn(r.x, __fmul_rn(0.5f, wdt));
    float cy  = __fadd_rn(r.y, __fmul_rn(0.5f, hgt));
    float gw  = __fadd_rn(__fsub_rn(gb.z, gb.x), 1.0f);
    float gh  = __fadd_rn(__fsub_rn(gb.w, gb.y), 1.0f);
    float gcx = __fadd_rn(gb.x, __fmul_rn(0.5f, gw));
    float gcy = __fadd_rn(gb.y, __fmul_rn(0.5f, gh));

    float d0 = __fdiv_rn(__fdiv_rn(__fsub_rn(gcx, cx), wdt), 0.2f);
    float d1 = __fdiv_rn(__fdiv_rn(__fsub_rn(gcy, cy), hgt), 0.2f);
    float d2 = __fdiv_rn(logf(__fdiv_rn(gw, wdt)), 0.2f);
    float d3 = __fdiv_rn(logf(__fdiv_rn(gh, hgt)), 0.2f);

    out[4 * pos + 0] = r.x;
    out[4 * pos + 1] = r.y;
    out[4 * pos + 2] = r.z;
    out[4 * pos + 3] = r.w;
    out[2048 + 4 * pos + 0] = d0;
    out[2048 + 4 * pos + 1] = d1;
    out[2048 + 4 * pos + 2] = d2;
    out[2048 + 4 * pos + 3] = d3;
    out[4096 + pos] = (float)labels[g];
}

extern "C" void kernel_launch(void* const* d_in, const int* in_sizes, int n_in,
                              void* d_out, int out_size, void* d_ws, size_t ws_size,
                              hipStream_t stream)
{
    const float* rois   = (const float*)d_in[0];
    const float* gt     = (const float*)d_in[1];
    const int*   labels = (const int*)d_in[2];
    float* out = (float*)d_out;

    char* ws = (char*)d_ws;
    uint16_t* packed = (uint16_t*)(ws + OFF_PACKED);
    uint32_t* cnt    = (uint32_t*)(ws + OFF_CNT);

    k_iou<<<NBLOCKS, BLK, 0, stream>>>(rois, gt, packed, cnt);
    k_select<<<NBLOCKS, BLK, 0, stream>>>(rois, gt, labels, packed, cnt, out);
}